// Round 3
// baseline (244.575 us; speedup 1.0000x reference)
//
#include <hip/hip_runtime.h>
#include <hip/hip_bf16.h>

// Problem: MLP_AE_72756745994415
// Key structural fact: the reference drops the ONES digit of i, so
// out[k,i] depends only on j = i/10. The 99,999-wide row is runs of 10
// identical values v(j), j in [0,10000), except i=0 (special) vs i=1..9.
//
//   j>=1000 (i>=10000): v = T4A[j/100] * B4[j%100]
//   j>= 100 (i>= 1000): v = T3A[j/10]  * B3[j%10]
//   j>=  10 (i>=  100): v = T2A[j]
//   j in 1..9 (i 10..99): v = x3[1]*x3[5+j]
//   j==0: i==0 -> x3[1]*x3[5];  i in 1..9 -> x3[0]
//
// Kernel A: x[512,512] -> MLP -> 6 group softmaxes -> x3[512,55] in d_ws.
// Kernel B: 512 rows x 8 slices = 4096 blocks; per-block LDS tables, then
// stream aligned float4 stores. 205 MB writes -> ~33 us HBM floor.

#define BATCH 512
#define DIM   512
#define HID   256
#define NCLS  55
#define NOUT  99999
#define LEAK  0.01f

__global__ __launch_bounds__(256) void mlp_x3_kernel(
    const float* __restrict__ x,  const float* __restrict__ w2,
    const float* __restrict__ b2, const float* __restrict__ w3,
    const float* __restrict__ b3, float* __restrict__ x3out) {
    __shared__ float xs[DIM];
    __shared__ float hs[HID];
    __shared__ float zp[4][NCLS];
    __shared__ float x3s[NCLS];

    const int tid = threadIdx.x;
    const int k   = blockIdx.x;

    xs[tid]       = x[(size_t)k * DIM + tid];
    xs[tid + 256] = x[(size_t)k * DIM + tid + 256];
    __syncthreads();

    // layer 1: thread t = neuron t; 4 independent accumulator chains
    {
        const float4* w2r = (const float4*)(w2 + (size_t)tid * DIM);
        const float4* xr  = (const float4*)xs;
        float4 a4 = make_float4(0.f, 0.f, 0.f, 0.f);
#pragma unroll 8
        for (int d4 = 0; d4 < DIM / 4; ++d4) {
            float4 w  = w2r[d4];
            float4 xv = xr[d4];
            a4.x += w.x * xv.x; a4.y += w.y * xv.y;
            a4.z += w.z * xv.z; a4.w += w.w * xv.w;
        }
        float acc = (a4.x + a4.y) + (a4.z + a4.w) + b2[tid];
        hs[tid] = (acc >= 0.f) ? acc : LEAK * acc;
    }
    __syncthreads();

    // layer 2: 220 threads, split-K (4 parts x 64)
    if (tid < 4 * NCLS) {
        int o = tid % NCLS, part = tid / NCLS;
        const float4* w3r = (const float4*)(w3 + (size_t)o * HID + part * 64);
        const float4* hr  = (const float4*)(hs + part * 64);
        float4 a4 = make_float4(0.f, 0.f, 0.f, 0.f);
#pragma unroll
        for (int d4 = 0; d4 < 16; ++d4) {
            float4 w = w3r[d4];
            float4 h = hr[d4];
            a4.x += w.x * h.x; a4.y += w.y * h.y;
            a4.z += w.z * h.z; a4.w += w.w * h.w;
        }
        zp[part][o] = (a4.x + a4.y) + (a4.z + a4.w);
    }
    __syncthreads();
    if (tid < NCLS)
        x3s[tid] = zp[0][tid] + zp[1][tid] + zp[2][tid] + zp[3][tid] + b3[tid];
    __syncthreads();

    // softmax: 6 groups (len 5, then 5x len 10)
    if (tid < 6) {
        int off = (tid == 0) ? 0 : 5 + 10 * (tid - 1);
        int len = (tid == 0) ? 5 : 10;
        float m = -1e30f;
        for (int u = 0; u < len; ++u) m = fmaxf(m, x3s[off + u]);
        float s = 0.f;
        for (int u = 0; u < len; ++u) {
            float e = __expf(x3s[off + u] - m);
            x3s[off + u] = e;
            s += e;
        }
        float inv = 1.f / s;
        for (int u = 0; u < len; ++u) x3s[off + u] *= inv;
    }
    __syncthreads();

    if (tid < NCLS) x3out[k * NCLS + tid] = x3s[tid];
}

__device__ __forceinline__ float Vj(
    unsigned j, const float* __restrict__ T4A, const float* __restrict__ T3A,
    const float* __restrict__ T2A, const float* __restrict__ B4,
    const float* __restrict__ B3,  const float* __restrict__ A1b) {
    if (j >= 1000u) { unsigned q = j / 100u; return T4A[q] * B4[j - q * 100u]; }
    if (j >= 100u)  { unsigned q = j / 10u;  return T3A[q] * B3[j - q * 10u]; }
    if (j >= 10u)   return T2A[j];
    return A1b[j];
}

// 512 rows x 8 slices; each slice covers in-row elements [s*12500, ...).
__global__ __launch_bounds__(256) void expand_kernel(
    const float* __restrict__ x3g, float* __restrict__ out) {
    __shared__ float T4A[100], T3A[100], T2A[100], B4[100];
    __shared__ float B3[16], A1b[16];
    __shared__ float x3s[NCLS];

    const int tid = threadIdx.x;
    const int k   = blockIdx.x >> 3;
    const int s   = blockIdx.x & 7;

    if (tid < NCLS) x3s[tid] = x3g[k * NCLS + tid];
    __syncthreads();

    if (tid < 100) {
        int hi = tid / 10, lo = tid % 10;
        float pp = x3s[5 + hi] * x3s[15 + lo];
        T4A[tid] = x3s[4] * pp;
        T3A[tid] = x3s[3] * pp;
        T2A[tid] = x3s[2] * pp;
        B4[tid]  = x3s[25 + hi] * x3s[35 + lo];
    } else if (tid < 110) {
        int d = tid - 100;
        B3[d]  = x3s[25 + d];
        A1b[d] = (d == 0) ? x3s[0] : x3s[1] * x3s[5 + d];
    }
    __syncthreads();

    const float pz = x3s[1] * x3s[5];   // the i==0 special value

    const unsigned e_lo = (unsigned)s * 12500u;
    const unsigned n_el = (s == 7) ? 12499u : 12500u;
    const size_t   gbase = (size_t)k * NOUT + e_lo;
    const unsigned head = (unsigned)((4u - ((unsigned)gbase & 3u)) & 3u);
    const unsigned ng   = (n_el - head) >> 2;
    const unsigned tail0 = head + (ng << 2);

    // scalar head/tail peel
    if (tid < (int)head) {
        unsigned i = e_lo + (unsigned)tid;
        float v = Vj(i / 10u, T4A, T3A, T2A, B4, B3, A1b);
        if (i == 0u) v = pz;
        out[gbase + tid] = v;
    }
    if (tid < (int)(n_el - tail0)) {
        unsigned e = tail0 + (unsigned)tid;
        unsigned i = e_lo + e;
        out[gbase + e] = Vj(i / 10u, T4A, T3A, T2A, B4, B3, A1b);
    }

    // aligned float4 body: 4 consecutive i span at most 2 decades
    float4* outv = (float4*)(out + gbase + head);
    for (unsigned g = tid; g < ng; g += 256) {
        unsigned i   = e_lo + head + (g << 2);
        unsigned j0  = i / 10u;
        unsigned rem = i - j0 * 10u;          // 0..9
        float v0 = Vj(j0, T4A, T3A, T2A, B4, B3, A1b);
        unsigned j1 = j0 + (rem >= 7u ? 1u : 0u);
        float v1 = Vj(j1, T4A, T3A, T2A, B4, B3, A1b);
        unsigned m = 10u - rem;               // elements using v0 (>=1)
        float4 v;
        v.x = (i == 0u) ? pz : v0;
        v.y = (1u < m) ? v0 : v1;
        v.z = (2u < m) ? v0 : v1;
        v.w = (3u < m) ? v0 : v1;
        outv[g] = v;
    }
}

extern "C" void kernel_launch(void* const* d_in, const int* in_sizes, int n_in,
                              void* d_out, int out_size, void* d_ws, size_t ws_size,
                              hipStream_t stream) {
    const float* x  = (const float*)d_in[0];
    const float* w2 = (const float*)d_in[1];
    const float* b2 = (const float*)d_in[2];
    const float* w3 = (const float*)d_in[3];
    const float* b3 = (const float*)d_in[4];
    float* out = (float*)d_out;
    float* x3  = (float*)d_ws;   // 512*55*4 = 112,640 B

    mlp_x3_kernel<<<BATCH, 256, 0, stream>>>(x, w2, b2, w3, b3, x3);
    expand_kernel<<<BATCH * 8, 256, 0, stream>>>(x3, out);
}

// Round 4
// 236.244 us; speedup vs baseline: 1.0353x; 1.0353x over previous
//
#include <hip/hip_runtime.h>
#include <hip/hip_bf16.h>

// Problem: MLP_AE_72756745994415
// out[k,i] depends only on j = i/10 (reference drops the ones digit):
//   j>=1000: T4A[j/100]*B4[j%100]; j>=100: T3A[j/10]*B3[j%10];
//   j>=10: T2A[j]; j in 1..9: x3[1]*x3[5+j]; j==0: i==0 -> x3[1]*x3[5], else x3[0]
//
// Kernel A (R4 rewrite): wave-per-neuron COALESCED GEMV.
//   Old: lane-strided w2 rows -> 32+ cache lines per load instr (~80 us).
//   New: per neuron, lanes read contiguous 1 KB chunks; shfl_xor reduce.
// Kernel B: unchanged from R3 (store-bound, proven at floor).

#define BATCH 512
#define DIM   512
#define HID   256
#define NCLS  55
#define NOUT  99999
#define LEAK  0.01f

__global__ __launch_bounds__(256) void mlp_x3_kernel(
    const float* __restrict__ x,  const float* __restrict__ w2,
    const float* __restrict__ b2, const float* __restrict__ w3,
    const float* __restrict__ b3, float* __restrict__ x3out) {
    __shared__ float xs[DIM];
    __shared__ float hs[HID];
    __shared__ float x3s[NCLS];

    const int tid  = threadIdx.x;
    const int k    = blockIdx.x;
    const int wave = tid >> 6;
    const int lane = tid & 63;

    xs[tid]       = x[(size_t)k * DIM + tid];
    xs[tid + 256] = x[(size_t)k * DIM + tid + 256];
    __syncthreads();

    // ---- layer 1: wave w computes neurons [64w, 64w+64); coalesced reads ----
    {
        // hoisted x fragments: lane l holds dims [4l,4l+4) and [256+4l, ...)
        float4 xv0 = ((const float4*)xs)[lane];
        float4 xv1 = ((const float4*)xs)[lane + 64];
        float  biasv = b2[wave * 64 + lane];
        float  acc = 0.f;
#pragma unroll 4
        for (int t = 0; t < 64; ++t) {
            const int n = wave * 64 + t;
            const float4* w2r = (const float4*)(w2 + (size_t)n * DIM);
            float4 a = w2r[lane];        // 1 KB contiguous across the wave
            float4 b = w2r[lane + 64];   // second KB
            float s = a.x * xv0.x + a.y * xv0.y + a.z * xv0.z + a.w * xv0.w
                    + b.x * xv1.x + b.y * xv1.y + b.z * xv1.z + b.w * xv1.w;
#pragma unroll
            for (int off = 1; off < 64; off <<= 1) s += __shfl_xor(s, off, 64);
            if (lane == t) acc = s;      // neuron t's total lands in lane t
        }
        float hv = acc + biasv;
        hs[wave * 64 + lane] = (hv >= 0.f) ? hv : LEAK * hv;
    }
    __syncthreads();

    // ---- layer 2: wave w handles outputs o = w, w+4, ...; coalesced ----
    {
        float4 hv = ((const float4*)hs)[lane];   // dims [4l, 4l+4)
        for (int o = wave; o < NCLS; o += 4) {
            const float4* w3r = (const float4*)(w3 + (size_t)o * HID);
            float4 w = w3r[lane];        // 1 KB contiguous
            float s = w.x * hv.x + w.y * hv.y + w.z * hv.z + w.w * hv.w;
#pragma unroll
            for (int off = 1; off < 64; off <<= 1) s += __shfl_xor(s, off, 64);
            if (lane == 0) x3s[o] = s + b3[o];
        }
    }
    __syncthreads();

    // ---- softmax: 6 groups (len 5, then 5x len 10) ----
    if (tid < 6) {
        int off = (tid == 0) ? 0 : 5 + 10 * (tid - 1);
        int len = (tid == 0) ? 5 : 10;
        float m = -1e30f;
        for (int u = 0; u < len; ++u) m = fmaxf(m, x3s[off + u]);
        float s = 0.f;
        for (int u = 0; u < len; ++u) {
            float e = __expf(x3s[off + u] - m);
            x3s[off + u] = e;
            s += e;
        }
        float inv = 1.f / s;
        for (int u = 0; u < len; ++u) x3s[off + u] *= inv;
    }
    __syncthreads();

    if (tid < NCLS) x3out[k * NCLS + tid] = x3s[tid];
}

__device__ __forceinline__ float Vj(
    unsigned j, const float* __restrict__ T4A, const float* __restrict__ T3A,
    const float* __restrict__ T2A, const float* __restrict__ B4,
    const float* __restrict__ B3,  const float* __restrict__ A1b) {
    if (j >= 1000u) { unsigned q = j / 100u; return T4A[q] * B4[j - q * 100u]; }
    if (j >= 100u)  { unsigned q = j / 10u;  return T3A[q] * B3[j - q * 10u]; }
    if (j >= 10u)   return T2A[j];
    return A1b[j];
}

// 512 rows x 8 slices; each slice covers in-row elements [s*12500, ...).
__global__ __launch_bounds__(256) void expand_kernel(
    const float* __restrict__ x3g, float* __restrict__ out) {
    __shared__ float T4A[100], T3A[100], T2A[100], B4[100];
    __shared__ float B3[16], A1b[16];
    __shared__ float x3s[NCLS];

    const int tid = threadIdx.x;
    const int k   = blockIdx.x >> 3;
    const int s   = blockIdx.x & 7;

    if (tid < NCLS) x3s[tid] = x3g[k * NCLS + tid];
    __syncthreads();

    if (tid < 100) {
        int hi = tid / 10, lo = tid % 10;
        float pp = x3s[5 + hi] * x3s[15 + lo];
        T4A[tid] = x3s[4] * pp;
        T3A[tid] = x3s[3] * pp;
        T2A[tid] = x3s[2] * pp;
        B4[tid]  = x3s[25 + hi] * x3s[35 + lo];
    } else if (tid < 110) {
        int d = tid - 100;
        B3[d]  = x3s[25 + d];
        A1b[d] = (d == 0) ? x3s[0] : x3s[1] * x3s[5 + d];
    }
    __syncthreads();

    const float pz = x3s[1] * x3s[5];   // the i==0 special value

    const unsigned e_lo = (unsigned)s * 12500u;
    const unsigned n_el = (s == 7) ? 12499u : 12500u;
    const size_t   gbase = (size_t)k * NOUT + e_lo;
    const unsigned head = (unsigned)((4u - ((unsigned)gbase & 3u)) & 3u);
    const unsigned ng   = (n_el - head) >> 2;
    const unsigned tail0 = head + (ng << 2);

    if (tid < (int)head) {
        unsigned i = e_lo + (unsigned)tid;
        float v = Vj(i / 10u, T4A, T3A, T2A, B4, B3, A1b);
        if (i == 0u) v = pz;
        out[gbase + tid] = v;
    }
    if (tid < (int)(n_el - tail0)) {
        unsigned e = tail0 + (unsigned)tid;
        unsigned i = e_lo + e;
        out[gbase + e] = Vj(i / 10u, T4A, T3A, T2A, B4, B3, A1b);
    }

    float4* outv = (float4*)(out + gbase + head);
    for (unsigned g = tid; g < ng; g += 256) {
        unsigned i   = e_lo + head + (g << 2);
        unsigned j0  = i / 10u;
        unsigned rem = i - j0 * 10u;          // 0..9
        float v0 = Vj(j0, T4A, T3A, T2A, B4, B3, A1b);
        unsigned j1 = j0 + (rem >= 7u ? 1u : 0u);
        float v1 = Vj(j1, T4A, T3A, T2A, B4, B3, A1b);
        unsigned m = 10u - rem;               // elements using v0 (>=1)
        float4 v;
        v.x = (i == 0u) ? pz : v0;
        v.y = (1u < m) ? v0 : v1;
        v.z = (2u < m) ? v0 : v1;
        v.w = (3u < m) ? v0 : v1;
        outv[g] = v;
    }
}

extern "C" void kernel_launch(void* const* d_in, const int* in_sizes, int n_in,
                              void* d_out, int out_size, void* d_ws, size_t ws_size,
                              hipStream_t stream) {
    const float* x  = (const float*)d_in[0];
    const float* w2 = (const float*)d_in[1];
    const float* b2 = (const float*)d_in[2];
    const float* w3 = (const float*)d_in[3];
    const float* b3 = (const float*)d_in[4];
    float* out = (float*)d_out;
    float* x3  = (float*)d_ws;   // 512*55*4 = 112,640 B

    mlp_x3_kernel<<<BATCH, 256, 0, stream>>>(x, w2, b2, w3, b3, x3);
    expand_kernel<<<BATCH * 8, 256, 0, stream>>>(x3, out);
}